// Round 3
// baseline (1233.302 us; speedup 1.0000x reference)
//
#include <hip/hip_runtime.h>
#include <hip/hip_bf16.h>
#include <cstdint>

// ---------------- constants ----------------
#define DIM     384
#define NHEADS  12
#define HD      32
#define HGRID   64          // H = W = 64
#define NTOK    64          // tokens per 8x8 window
#define MTOT    65536       // 16 * 4096 rows
#define HID     1536

typedef __attribute__((ext_vector_type(8))) short bf16x8;
typedef __attribute__((ext_vector_type(4))) float f32x4;
typedef __hip_bfloat16 bf16;

typedef __attribute__((address_space(1))) const void* as1_cvp;
typedef __attribute__((address_space(3))) void*       as3_vp;
#define GLDS16(g, l) __builtin_amdgcn_global_load_lds((as1_cvp)(g), (as3_vp)(l), 16, 0, 0)

// ---------------- K0: weight fp32 (KxN) -> bf16 transposed (NxK) ----------------
__global__ void wconv_kernel(const float* __restrict__ src, bf16* __restrict__ dst,
                             int K, int N) {
  int i = blockIdx.x * 256 + threadIdx.x;
  if (i >= K * N) return;
  int n = i / K, k = i - n * K;
  dst[i] = __float2bfloat16(src[(size_t)k * N + n]);
}

// ---------------- K1/K5: LayerNorm (optionally fused roll+window gather) ----------
// blockIdx.x = OUTPUT row; 384 threads = one per channel.
__global__ __launch_bounds__(384) void ln_kernel(const float* __restrict__ x,
    const float* __restrict__ g, const float* __restrict__ bta,
    bf16* __restrict__ out, int windowed) {
  const int row = blockIdx.x;
  const int c = threadIdx.x;
  size_t src;
  if (windowed) {
    int wg = row >> 6, n = row & 63;
    int b = wg >> 6, wi = wg & 63;
    int hp = ((wi >> 3) << 3) + (n >> 3);
    int wp = ((wi & 7) << 3) + (n & 7);
    int h = (hp + 4) & 63, w = (wp + 4) & 63;   // roll(-4): rolled[i] = x[(i+4)%64]
    src = ((size_t)b * 4096 + h * 64 + w) * DIM;
  } else {
    src = (size_t)row * DIM;
  }
  float v = x[src + c];
  float s = v, ss = v * v;
  #pragma unroll
  for (int off = 32; off; off >>= 1) {
    s  += __shfl_xor(s,  off, 64);
    ss += __shfl_xor(ss, off, 64);
  }
  __shared__ float red[12];
  const int wave = threadIdx.x >> 6, lane = threadIdx.x & 63;
  if (lane == 0) { red[wave] = s; red[6 + wave] = ss; }
  __syncthreads();
  if (threadIdx.x == 0) {
    float ts = 0.f, tss = 0.f;
    #pragma unroll
    for (int i = 0; i < 6; i++) { ts += red[i]; tss += red[6 + i]; }
    red[0] = ts; red[6] = tss;
  }
  __syncthreads();
  const float mean = red[0] * (1.0f / DIM);
  const float var  = red[6] * (1.0f / DIM) - mean * mean;
  const float inv  = rsqrtf(var + 1e-5f);
  out[(size_t)row * DIM + c] = __float2bfloat16((v - mean) * inv * g[c] + bta[c]);
}

// ---------------- GEMM: C = A(MxK) * Bt(NxK)^T, bf16 MFMA 16x16x32 ---------------
// 128x128 tile, BK=64, 4 waves (each 64x64).
// A: global_load_lds width-16 into 128x64 LDS tile (16 KB), chunk-XOR swizzled:
//    slot s of row R holds global 16B-chunk s ^ (R&7) -> frag reads are 2-way (free).
// B: weights are tiny (<=1.2 MB, L2-resident) and have zero intra-block reuse
//    across waves' registers -> load fragments DIRECTLY global->VGPR (dwordx4),
//    skipping LDS entirely. Halves LDS traffic + vmcnt drain depth per barrier.
// EPI: 0 = +bias -> bf16 out
//      1 = +bias, exact GELU -> bf16 out
//      2 = +bias, window-reverse+roll scatter, + residual x -> f32 out
//      3 = +bias, += into f32 out (row-major)
template <int EPI>
__global__ __launch_bounds__(256) void gemm_bt(
    const bf16* __restrict__ A, const bf16* __restrict__ Bt,
    const float* __restrict__ bias,
    bf16* __restrict__ outb, float* __restrict__ outf,
    const float* __restrict__ resid,
    int M, int N, int K)
{
  __shared__ bf16 As[128 * 64];   // 16 KB, row stride 64 elems (128 B = 8 chunks)
  const int tid = threadIdx.x;
  const int wave = tid >> 6, lane = tid & 63;
  const int m0 = blockIdx.y * 128, n0 = blockIdx.x * 128;

  f32x4 acc[4][4];
  #pragma unroll
  for (int i = 0; i < 4; i++)
    #pragma unroll
    for (int j = 0; j < 4; j++) acc[i][j] = (f32x4){0.f, 0.f, 0.f, 0.f};

  const int q = lane >> 4, r = lane & 15;
  const int mwav = (wave >> 1) * 64, nwav = (wave & 1) * 64;

  // A staging: wave stages rows [wave*32, wave*32+32), 4 GLDS16 of 8 rows each.
  // lane l -> dest row base+ (l>>3), slot l&7; source chunk g = (l&7) ^ ((l>>3)&7)
  const int srow = wave * 32 + (lane >> 3);
  const int gchunk = (lane & 7) ^ ((lane >> 3) & 7);
  const char* Ac = (const char*)A + (size_t)(m0 + srow) * K * 2 + gchunk * 16;
  const size_t rowskip8 = (size_t)8 * K * 2;

  // B direct per-lane base: row n0+nwav+r, k-offset q*8
  const bf16* Bp = Bt + (size_t)(n0 + nwav + r) * K + q * 8;

  const int rxor = r & 7;

  for (int k0 = 0; k0 < K; k0 += 64) {
    const size_t kb = (size_t)k0 * 2;
    GLDS16(Ac + kb,                 &As[(wave * 32 +  0) * 64]);
    GLDS16(Ac + kb + rowskip8,      &As[(wave * 32 +  8) * 64]);
    GLDS16(Ac + kb + 2 * rowskip8,  &As[(wave * 32 + 16) * 64]);
    GLDS16(Ac + kb + 3 * rowskip8,  &As[(wave * 32 + 24) * 64]);
    __syncthreads();

    #pragma unroll
    for (int hh = 0; hh < 2; hh++) {
      bf16x8 af[4], bfr[4];
      #pragma unroll
      for (int mi = 0; mi < 4; mi++) {
        const int R = mwav + mi * 16 + r;
        const int s = (hh * 4 + q) ^ rxor;
        af[mi] = *(const bf16x8*)(&As[R * 64 + s * 8]);
      }
      #pragma unroll
      for (int ni = 0; ni < 4; ni++)
        bfr[ni] = *(const bf16x8*)(Bp + (size_t)ni * 16 * K + k0 + hh * 32);
      #pragma unroll
      for (int mi = 0; mi < 4; mi++)
        #pragma unroll
        for (int ni = 0; ni < 4; ni++)
          acc[mi][ni] = __builtin_amdgcn_mfma_f32_16x16x32_bf16(af[mi], bfr[ni], acc[mi][ni], 0, 0, 0);
    }
    __syncthreads();
  }

  // epilogue: D row = (lane>>4)*4 + reg (M), col = lane&15 (N)  [m89-verified]
  #pragma unroll
  for (int mi = 0; mi < 4; mi++) {
    #pragma unroll
    for (int ni = 0; ni < 4; ni++) {
      #pragma unroll
      for (int rr = 0; rr < 4; rr++) {
        const int row = m0 + mwav + mi * 16 + q * 4 + rr;
        const int col = n0 + nwav + ni * 16 + r;
        float val = acc[mi][ni][rr] + bias[col];
        if (EPI == 0) {
          outb[(size_t)row * N + col] = __float2bfloat16(val);
        } else if (EPI == 1) {
          float gl = 0.5f * val * (1.0f + erff(val * 0.70710678118654752f));
          outb[(size_t)row * N + col] = __float2bfloat16(gl);
        } else if (EPI == 2) {
          const int wg = row >> 6, n = row & 63;
          const int b = wg >> 6, wi = wg & 63;
          const int hp = ((wi >> 3) << 3) + (n >> 3);
          const int wp = ((wi & 7) << 3) + (n & 7);
          const int h = (hp + 4) & 63, w = (wp + 4) & 63;  // roll(+4): final[(i+4)%64]=tmp[i]
          const size_t dst = ((size_t)b * 4096 + h * 64 + w) * DIM + col;
          outf[dst] = resid[dst] + val;
        } else {
          outf[(size_t)row * N + col] += val;
        }
      }
    }
  }
}

// ---------------- K3: windowed attention, one block per (window, head) -----------
__device__ __forceinline__ int regid(int v) { return v < 56 ? 0 : (v < 60 ? 1 : 2); }

__global__ __launch_bounds__(256) void attn_kernel(
    const bf16* __restrict__ qkv, const float* __restrict__ tau,
    const float* __restrict__ rpb, bf16* __restrict__ outb)
{
  const int h = blockIdx.x;          // head
  const int w = blockIdx.y;          // global window (b*64 + wy*8 + wx)
  const int t = threadIdx.x;
  const int row = t >> 2, seg = t & 3;

  __shared__ float qs[64][36];
  __shared__ float ks[64][36];
  __shared__ float vs[64][36];
  __shared__ float rpb_s[225];

  // load q/k/v (8 dims per thread), fused l2norm + tau scale
  const size_t base = ((size_t)w * 64 + row) * 1152 + h * 32 + seg * 8;
  float qf[8], kf[8], vf[8];
  {
    uint4 uq = *(const uint4*)(qkv + base);
    uint4 uk = *(const uint4*)(qkv + base + 384);
    uint4 uv = *(const uint4*)(qkv + base + 768);
    const bf16* pq = (const bf16*)&uq;
    const bf16* pk = (const bf16*)&uk;
    const bf16* pv = (const bf16*)&uv;
    #pragma unroll
    for (int i = 0; i < 8; i++) {
      qf[i] = __bfloat162float(pq[i]);
      kf[i] = __bfloat162float(pk[i]);
      vf[i] = __bfloat162float(pv[i]);
    }
  }
  float ssq = 0.f, ssk = 0.f;
  #pragma unroll
  for (int i = 0; i < 8; i++) { ssq += qf[i] * qf[i]; ssk += kf[i] * kf[i]; }
  ssq += __shfl_xor(ssq, 1, 64); ssq += __shfl_xor(ssq, 2, 64);
  ssk += __shfl_xor(ssk, 1, 64); ssk += __shfl_xor(ssk, 2, 64);
  const float qsc = (1.0f / fmaxf(sqrtf(ssq), 1e-12f)) * (1.0f / fmaxf(tau[h], 1e-3f));
  const float ksc = 1.0f / fmaxf(sqrtf(ssk), 1e-12f);
  #pragma unroll
  for (int i = 0; i < 8; i++) {
    qs[row][seg * 8 + i] = qf[i] * qsc;
    ks[row][seg * 8 + i] = kf[i] * ksc;
    vs[row][seg * 8 + i] = vf[i];
  }
  if (t < 225) rpb_s[t] = rpb[t * NHEADS + h];
  __syncthreads();

  float4 qr[8];
  #pragma unroll
  for (int u = 0; u < 8; u++) qr[u] = *(const float4*)&qs[row][u * 4];

  const int wi = w & 63;
  const int wy = wi >> 3, wx = wi & 7;
  const int iy = row >> 3, ix = row & 7;
  const int reg_i = regid(wy * 8 + iy) * 3 + regid(wx * 8 + ix);

  // scores for this row, j = jj*4 + seg (bank-conflict-free interleave)
  float sv[16];
  float mx = -3e38f;
  #pragma unroll
  for (int jj = 0; jj < 16; jj++) {
    const int j = jj * 4 + seg;
    const float4* kr = (const float4*)&ks[j][0];
    float dot = 0.f;
    #pragma unroll
    for (int u = 0; u < 8; u++) {
      float4 kk = kr[u];
      dot += qr[u].x * kk.x; dot += qr[u].y * kk.y;
      dot += qr[u].z * kk.z; dot += qr[u].w * kk.w;
    }
    const int jy = j >> 3, jx = j & 7;
    dot += rpb_s[(iy - jy + 7) * 15 + (ix - jx + 7)];
    const int reg_j = regid(wy * 8 + jy) * 3 + regid(wx * 8 + jx);
    if (reg_j != reg_i) dot -= 1e9f;
    sv[jj] = dot;
    mx = fmaxf(mx, dot);
  }
  mx = fmaxf(mx, __shfl_xor(mx, 1, 64));
  mx = fmaxf(mx, __shfl_xor(mx, 2, 64));
  float sum = 0.f;
  #pragma unroll
  for (int jj = 0; jj < 16; jj++) { sv[jj] = __expf(sv[jj] - mx); sum += sv[jj]; }
  sum += __shfl_xor(sum, 1, 64); sum += __shfl_xor(sum, 2, 64);
  const float rinv = 1.0f / sum;

  float4 po[8];
  #pragma unroll
  for (int u = 0; u < 8; u++) po[u] = make_float4(0.f, 0.f, 0.f, 0.f);
  #pragma unroll
  for (int jj = 0; jj < 16; jj++) {
    const float p = sv[jj] * rinv;
    const float4* vr = (const float4*)&vs[jj * 4 + seg][0];
    #pragma unroll
    for (int u = 0; u < 8; u++) {
      float4 vv = vr[u];
      po[u].x += p * vv.x; po[u].y += p * vv.y;
      po[u].z += p * vv.z; po[u].w += p * vv.w;
    }
  }
  #pragma unroll
  for (int u = 0; u < 8; u++) {
    po[u].x += __shfl_xor(po[u].x, 1, 64); po[u].x += __shfl_xor(po[u].x, 2, 64);
    po[u].y += __shfl_xor(po[u].y, 1, 64); po[u].y += __shfl_xor(po[u].y, 2, 64);
    po[u].z += __shfl_xor(po[u].z, 1, 64); po[u].z += __shfl_xor(po[u].z, 2, 64);
    po[u].w += __shfl_xor(po[u].w, 1, 64); po[u].w += __shfl_xor(po[u].w, 2, 64);
  }
  // each thread writes its 8 dims: float4 indices seg*2, seg*2+1 (static select)
  float4 o0, o1;
  switch (seg) {
    case 0: o0 = po[0]; o1 = po[1]; break;
    case 1: o0 = po[2]; o1 = po[3]; break;
    case 2: o0 = po[4]; o1 = po[5]; break;
    default: o0 = po[6]; o1 = po[7]; break;
  }
  union { uint4 u; bf16 b[8]; } ou;
  ou.b[0] = __float2bfloat16(o0.x); ou.b[1] = __float2bfloat16(o0.y);
  ou.b[2] = __float2bfloat16(o0.z); ou.b[3] = __float2bfloat16(o0.w);
  ou.b[4] = __float2bfloat16(o1.x); ou.b[5] = __float2bfloat16(o1.y);
  ou.b[6] = __float2bfloat16(o1.z); ou.b[7] = __float2bfloat16(o1.w);
  *(uint4*)(outb + ((size_t)w * 64 + row) * DIM + h * 32 + seg * 8) = ou.u;
}

// ---------------- host launch ----------------
extern "C" void kernel_launch(void* const* d_in, const int* in_sizes, int n_in,
                              void* d_out, int out_size, void* d_ws, size_t ws_size,
                              hipStream_t stream) {
  const float* x      = (const float*)d_in[0];
  const float* ln1_g  = (const float*)d_in[3];
  const float* ln1_b  = (const float*)d_in[4];
  const float* qkv_w  = (const float*)d_in[5];
  const float* qkv_b  = (const float*)d_in[6];
  const float* proj_w = (const float*)d_in[7];
  const float* proj_b = (const float*)d_in[8];
  const float* tau    = (const float*)d_in[9];
  const float* rpb    = (const float*)d_in[10];
  const float* ln2_g  = (const float*)d_in[11];
  const float* ln2_b  = (const float*)d_in[12];
  const float* fc1_w  = (const float*)d_in[13];
  const float* fc1_b  = (const float*)d_in[14];
  const float* fc2_w  = (const float*)d_in[15];
  const float* fc2_b  = (const float*)d_in[16];
  float* out = (float*)d_out;
  char* ws = (char*)d_ws;

  // workspace layout (peak ~244 MiB, buffers reused)
  bf16* wT_qkv  = (bf16*)(ws + 0);            //  884,736 B (1152x384)
  bf16* wT_proj = (bf16*)(ws + 884736);       //  294,912 B (384x384)
  bf16* wT_fc1  = (bf16*)(ws + 1179648);      // 1,179,648 B (1536x384)
  bf16* wT_fc2  = (bf16*)(ws + 2359296);      // 1,179,648 B (384x1536)
  bf16* winb    = (bf16*)(ws + 4194304);      // 50,331,648 B (65536x384)
  bf16* qkvb    = (bf16*)(ws + 54525952);     // 150,994,944 B (65536x1152)
  bf16* attnb   = (bf16*)(ws + 205520896);    // 50,331,648 B (65536x384)
  bf16* xn2b    = winb;                        // reuse (win dead after qkv GEMM)
  bf16* hb      = qkvb;                        // reuse (qkv+attn dead) 201,326,592 B

  // K0: weight conversion+transpose
  wconv_kernel<<<(384 * 1152 + 255) / 256, 256, 0, stream>>>(qkv_w, wT_qkv, 384, 1152);
  wconv_kernel<<<(384 * 384 + 255) / 256, 256, 0, stream>>>(proj_w, wT_proj, 384, 384);
  wconv_kernel<<<(384 * 1536 + 255) / 256, 256, 0, stream>>>(fc1_w, wT_fc1, 384, 1536);
  wconv_kernel<<<(1536 * 384 + 255) / 256, 256, 0, stream>>>(fc2_w, wT_fc2, 1536, 384);

  // K1: LN1 + roll + window partition
  ln_kernel<<<MTOT, 384, 0, stream>>>(x, ln1_g, ln1_b, winb, 1);
  // K2: qkv GEMM (65536 x 1152 x 384)
  gemm_bt<0><<<dim3(1152 / 128, MTOT / 128), 256, 0, stream>>>(
      winb, wT_qkv, qkv_b, qkvb, nullptr, nullptr, MTOT, 1152, 384);
  // K3: attention
  attn_kernel<<<dim3(NHEADS, 1024), 256, 0, stream>>>(qkvb, tau, rpb, attnb);
  // K4: proj GEMM + window-reverse/roll scatter + residual -> d_out
  gemm_bt<2><<<dim3(384 / 128, MTOT / 128), 256, 0, stream>>>(
      attnb, wT_proj, proj_b, nullptr, out, x, MTOT, 384, 384);
  // K5: LN2
  ln_kernel<<<MTOT, 384, 0, stream>>>(out, ln2_g, ln2_b, xn2b, 0);
  // K6: fc1 + GELU
  gemm_bt<1><<<dim3(HID / 128, MTOT / 128), 256, 0, stream>>>(
      xn2b, wT_fc1, fc1_b, hb, nullptr, nullptr, MTOT, HID, 384);
  // K7: fc2 += into d_out
  gemm_bt<3><<<dim3(384 / 128, MTOT / 128), 256, 0, stream>>>(
      hb, wT_fc2, fc2_b, nullptr, out, nullptr, MTOT, 384, HID);
}

// Round 4
// 988.721 us; speedup vs baseline: 1.2474x; 1.2474x over previous
//
#include <hip/hip_runtime.h>
#include <hip/hip_bf16.h>
#include <cstdint>

// ---------------- constants ----------------
#define DIM     384
#define NHEADS  12
#define HD      32
#define HGRID   64          // H = W = 64
#define NTOK    64          // tokens per 8x8 window
#define MTOT    65536       // 16 * 4096 rows
#define HID     1536

typedef __attribute__((ext_vector_type(8))) short bf16x8;
typedef __attribute__((ext_vector_type(4))) float f32x4;
typedef __hip_bfloat16 bf16;

typedef __attribute__((address_space(1))) const void* as1_cvp;
typedef __attribute__((address_space(3))) void*       as3_vp;
#define GLDS16(g, l) __builtin_amdgcn_global_load_lds((as1_cvp)(g), (as3_vp)(l), 16, 0, 0)

// ---------------- K0: weight fp32 (KxN) -> bf16 transposed (NxK) ----------------
__global__ void wconv_kernel(const float* __restrict__ src, bf16* __restrict__ dst,
                             int K, int N) {
  int i = blockIdx.x * 256 + threadIdx.x;
  if (i >= K * N) return;
  int n = i / K, k = i - n * K;
  dst[i] = __float2bfloat16(src[(size_t)k * N + n]);
}

// ---------------- K1/K5: LayerNorm (optionally fused roll+window gather) ----------
// blockIdx.x = OUTPUT row; 384 threads = one per channel.
__global__ __launch_bounds__(384) void ln_kernel(const float* __restrict__ x,
    const float* __restrict__ g, const float* __restrict__ bta,
    bf16* __restrict__ out, int windowed) {
  const int row = blockIdx.x;
  const int c = threadIdx.x;
  size_t src;
  if (windowed) {
    int wg = row >> 6, n = row & 63;
    int b = wg >> 6, wi = wg & 63;
    int hp = ((wi >> 3) << 3) + (n >> 3);
    int wp = ((wi & 7) << 3) + (n & 7);
    int h = (hp + 4) & 63, w = (wp + 4) & 63;   // roll(-4): rolled[i] = x[(i+4)%64]
    src = ((size_t)b * 4096 + h * 64 + w) * DIM;
  } else {
    src = (size_t)row * DIM;
  }
  float v = x[src + c];
  float s = v, ss = v * v;
  #pragma unroll
  for (int off = 32; off; off >>= 1) {
    s  += __shfl_xor(s,  off, 64);
    ss += __shfl_xor(ss, off, 64);
  }
  __shared__ float red[12];
  const int wave = threadIdx.x >> 6, lane = threadIdx.x & 63;
  if (lane == 0) { red[wave] = s; red[6 + wave] = ss; }
  __syncthreads();
  if (threadIdx.x == 0) {
    float ts = 0.f, tss = 0.f;
    #pragma unroll
    for (int i = 0; i < 6; i++) { ts += red[i]; tss += red[6 + i]; }
    red[0] = ts; red[6] = tss;
  }
  __syncthreads();
  const float mean = red[0] * (1.0f / DIM);
  const float var  = red[6] * (1.0f / DIM) - mean * mean;
  const float inv  = rsqrtf(var + 1e-5f);
  out[(size_t)row * DIM + c] = __float2bfloat16((v - mean) * inv * g[c] + bta[c]);
}

// ---------------- GEMM: C = A(MxK) * Bt(NxK)^T, bf16 MFMA 16x16x32 ---------------
// 128x128 tile, BK=32, 4 waves (each 64x64), global_load_lds width-16 staging.
// LDS k-chunk XOR swizzle (R1, conflicts=0 verified): slot c of row R holds
// global chunk c ^ ((R>>1)&3); read quad q from slot q ^ ((r>>1)&3).
// XCD-aware 1-D grid remap: hardware assigns linear block ids round-robin over
// 8 XCDs; map so all gridN N-blocks of one M-block are CONSECUTIVE SLOTS ON ONE
// XCD -> A tile is fetched from HBM once and re-read from that XCD's L2.
// EPI: 0 = +bias -> bf16 out
//      1 = +bias, exact GELU -> bf16 out
//      2 = +bias, window-reverse+roll scatter, + residual x -> f32 out
//      3 = +bias, += into f32 out (row-major)
template <int EPI>
__global__ __launch_bounds__(256) void gemm_bt(
    const bf16* __restrict__ A, const bf16* __restrict__ Bt,
    const float* __restrict__ bias,
    bf16* __restrict__ outb, float* __restrict__ outf,
    const float* __restrict__ resid,
    int M, int N, int K, int gridN)
{
  __shared__ bf16 As[128 * 32];
  __shared__ bf16 Bs[128 * 32];
  const int tid = threadIdx.x;
  const int wave = tid >> 6, lane = tid & 63;

  // XCD-aware remap (gridM = M/128 divisible by 8)
  const int bid = blockIdx.x;
  const int xcd = bid & 7, slot = bid >> 3;
  const int n_blk = slot % gridN;
  const int m_blk = (slot / gridN) * 8 + xcd;
  const int m0 = m_blk * 128, n0 = n_blk * 128;

  f32x4 acc[4][4];
  #pragma unroll
  for (int i = 0; i < 4; i++)
    #pragma unroll
    for (int j = 0; j < 4; j++) acc[i][j] = (f32x4){0.f, 0.f, 0.f, 0.f};

  const int q = lane >> 4, r = lane & 15;
  const int mwav = (wave >> 1) * 64, nwav = (wave & 1) * 64;

  // staging: per wave 32 rows of A and of Bt; each inst = 16 rows x 64B.
  // source chunk = (lane&3) ^ p(srow), p(srow) = (srow>>1)&3 = (lane>>3)&3
  const int srow = wave * 32 + (lane >> 2);
  const int schunk = (lane & 3) ^ ((lane >> 3) & 3);
  const size_t acol = (size_t)schunk * 16;       // byte offset within 64B k-slab
  const char* Ac = (const char*)A + (size_t)(m0 + srow) * K * 2 + acol;
  const char* Bc = (const char*)Bt + (size_t)(n0 + srow) * K * 2 + acol;
  const size_t rowskip = (size_t)16 * K * 2;

  // read-side swizzled chunk slot for this lane's quad
  const int rchunk = q ^ ((r >> 1) & 3);

  for (int k0 = 0; k0 < K; k0 += 32) {
    const size_t kb = (size_t)k0 * 2;
    GLDS16(Ac + kb,            &As[(wave * 32) * 32]);
    GLDS16(Ac + kb + rowskip,  &As[(wave * 32 + 16) * 32]);
    GLDS16(Bc + kb,            &Bs[(wave * 32) * 32]);
    GLDS16(Bc + kb + rowskip,  &Bs[(wave * 32 + 16) * 32]);
    __syncthreads();

    bf16x8 af[4], bfr[4];
    #pragma unroll
    for (int mi = 0; mi < 4; mi++)
      af[mi] = *(const bf16x8*)(&As[(mwav + mi * 16 + r) * 32 + rchunk * 8]);
    #pragma unroll
    for (int ni = 0; ni < 4; ni++)
      bfr[ni] = *(const bf16x8*)(&Bs[(nwav + ni * 16 + r) * 32 + rchunk * 8]);
    #pragma unroll
    for (int mi = 0; mi < 4; mi++)
      #pragma unroll
      for (int ni = 0; ni < 4; ni++)
        acc[mi][ni] = __builtin_amdgcn_mfma_f32_16x16x32_bf16(af[mi], bfr[ni], acc[mi][ni], 0, 0, 0);
    __syncthreads();
  }

  // epilogue: D row = (lane>>4)*4 + reg (M), col = lane&15 (N)  [m89-verified]
  #pragma unroll
  for (int mi = 0; mi < 4; mi++) {
    #pragma unroll
    for (int ni = 0; ni < 4; ni++) {
      #pragma unroll
      for (int rr = 0; rr < 4; rr++) {
        const int row = m0 + mwav + mi * 16 + q * 4 + rr;
        const int col = n0 + nwav + ni * 16 + r;
        float val = acc[mi][ni][rr] + bias[col];
        if (EPI == 0) {
          outb[(size_t)row * N + col] = __float2bfloat16(val);
        } else if (EPI == 1) {
          float gl = 0.5f * val * (1.0f + erff(val * 0.70710678118654752f));
          outb[(size_t)row * N + col] = __float2bfloat16(gl);
        } else if (EPI == 2) {
          const int wg = row >> 6, n = row & 63;
          const int b = wg >> 6, wi = wg & 63;
          const int hp = ((wi >> 3) << 3) + (n >> 3);
          const int wp = ((wi & 7) << 3) + (n & 7);
          const int h = (hp + 4) & 63, w = (wp + 4) & 63;  // roll(+4): final[(i+4)%64]=tmp[i]
          const size_t dst = ((size_t)b * 4096 + h * 64 + w) * DIM + col;
          outf[dst] = resid[dst] + val;
        } else {
          outf[(size_t)row * N + col] += val;
        }
      }
    }
  }
}

// ---------------- K3: windowed attention, one block per (window, head) -----------
__device__ __forceinline__ int regid(int v) { return v < 56 ? 0 : (v < 60 ? 1 : 2); }

__global__ __launch_bounds__(256) void attn_kernel(
    const bf16* __restrict__ qkv, const float* __restrict__ tau,
    const float* __restrict__ rpb, bf16* __restrict__ outb)
{
  const int h = blockIdx.x;          // head
  const int w = blockIdx.y;          // global window (b*64 + wy*8 + wx)
  const int t = threadIdx.x;
  const int row = t >> 2, seg = t & 3;

  __shared__ float qs[64][36];
  __shared__ float ks[64][36];
  __shared__ float vs[64][36];
  __shared__ float rpb_s[225];

  // load q/k/v (8 dims per thread), fused l2norm + tau scale
  const size_t base = ((size_t)w * 64 + row) * 1152 + h * 32 + seg * 8;
  float qf[8], kf[8], vf[8];
  {
    uint4 uq = *(const uint4*)(qkv + base);
    uint4 uk = *(const uint4*)(qkv + base + 384);
    uint4 uv = *(const uint4*)(qkv + base + 768);
    const bf16* pq = (const bf16*)&uq;
    const bf16* pk = (const bf16*)&uk;
    const bf16* pv = (const bf16*)&uv;
    #pragma unroll
    for (int i = 0; i < 8; i++) {
      qf[i] = __bfloat162float(pq[i]);
      kf[i] = __bfloat162float(pk[i]);
      vf[i] = __bfloat162float(pv[i]);
    }
  }
  float ssq = 0.f, ssk = 0.f;
  #pragma unroll
  for (int i = 0; i < 8; i++) { ssq += qf[i] * qf[i]; ssk += kf[i] * kf[i]; }
  ssq += __shfl_xor(ssq, 1, 64); ssq += __shfl_xor(ssq, 2, 64);
  ssk += __shfl_xor(ssk, 1, 64); ssk += __shfl_xor(ssk, 2, 64);
  const float qsc = (1.0f / fmaxf(sqrtf(ssq), 1e-12f)) * (1.0f / fmaxf(tau[h], 1e-3f));
  const float ksc = 1.0f / fmaxf(sqrtf(ssk), 1e-12f);
  #pragma unroll
  for (int i = 0; i < 8; i++) {
    qs[row][seg * 8 + i] = qf[i] * qsc;
    ks[row][seg * 8 + i] = kf[i] * ksc;
    vs[row][seg * 8 + i] = vf[i];
  }
  if (t < 225) rpb_s[t] = rpb[t * NHEADS + h];
  __syncthreads();

  float4 qr[8];
  #pragma unroll
  for (int u = 0; u < 8; u++) qr[u] = *(const float4*)&qs[row][u * 4];

  const int wi = w & 63;
  const int wy = wi >> 3, wx = wi & 7;
  const int iy = row >> 3, ix = row & 7;
  const int reg_i = regid(wy * 8 + iy) * 3 + regid(wx * 8 + ix);

  // scores for this row, j = jj*4 + seg (bank-conflict-free interleave)
  float sv[16];
  float mx = -3e38f;
  #pragma unroll
  for (int jj = 0; jj < 16; jj++) {
    const int j = jj * 4 + seg;
    const float4* kr = (const float4*)&ks[j][0];
    float dot = 0.f;
    #pragma unroll
    for (int u = 0; u < 8; u++) {
      float4 kk = kr[u];
      dot += qr[u].x * kk.x; dot += qr[u].y * kk.y;
      dot += qr[u].z * kk.z; dot += qr[u].w * kk.w;
    }
    const int jy = j >> 3, jx = j & 7;
    dot += rpb_s[(iy - jy + 7) * 15 + (ix - jx + 7)];
    const int reg_j = regid(wy * 8 + jy) * 3 + regid(wx * 8 + jx);
    if (reg_j != reg_i) dot -= 1e9f;
    sv[jj] = dot;
    mx = fmaxf(mx, dot);
  }
  mx = fmaxf(mx, __shfl_xor(mx, 1, 64));
  mx = fmaxf(mx, __shfl_xor(mx, 2, 64));
  float sum = 0.f;
  #pragma unroll
  for (int jj = 0; jj < 16; jj++) { sv[jj] = __expf(sv[jj] - mx); sum += sv[jj]; }
  sum += __shfl_xor(sum, 1, 64); sum += __shfl_xor(sum, 2, 64);
  const float rinv = 1.0f / sum;

  float4 po[8];
  #pragma unroll
  for (int u = 0; u < 8; u++) po[u] = make_float4(0.f, 0.f, 0.f, 0.f);
  #pragma unroll
  for (int jj = 0; jj < 16; jj++) {
    const float p = sv[jj] * rinv;
    const float4* vr = (const float4*)&vs[jj * 4 + seg][0];
    #pragma unroll
    for (int u = 0; u < 8; u++) {
      float4 vv = vr[u];
      po[u].x += p * vv.x; po[u].y += p * vv.y;
      po[u].z += p * vv.z; po[u].w += p * vv.w;
    }
  }
  #pragma unroll
  for (int u = 0; u < 8; u++) {
    po[u].x += __shfl_xor(po[u].x, 1, 64); po[u].x += __shfl_xor(po[u].x, 2, 64);
    po[u].y += __shfl_xor(po[u].y, 1, 64); po[u].y += __shfl_xor(po[u].y, 2, 64);
    po[u].z += __shfl_xor(po[u].z, 1, 64); po[u].z += __shfl_xor(po[u].z, 2, 64);
    po[u].w += __shfl_xor(po[u].w, 1, 64); po[u].w += __shfl_xor(po[u].w, 2, 64);
  }
  // each thread writes its 8 dims: float4 indices seg*2, seg*2+1 (static select)
  float4 o0, o1;
  switch (seg) {
    case 0: o0 = po[0]; o1 = po[1]; break;
    case 1: o0 = po[2]; o1 = po[3]; break;
    case 2: o0 = po[4]; o1 = po[5]; break;
    default: o0 = po[6]; o1 = po[7]; break;
  }
  union { uint4 u; bf16 b[8]; } ou;
  ou.b[0] = __float2bfloat16(o0.x); ou.b[1] = __float2bfloat16(o0.y);
  ou.b[2] = __float2bfloat16(o0.z); ou.b[3] = __float2bfloat16(o0.w);
  ou.b[4] = __float2bfloat16(o1.x); ou.b[5] = __float2bfloat16(o1.y);
  ou.b[6] = __float2bfloat16(o1.z); ou.b[7] = __float2bfloat16(o1.w);
  *(uint4*)(outb + ((size_t)w * 64 + row) * DIM + h * 32 + seg * 8) = ou.u;
}

// ---------------- host launch ----------------
extern "C" void kernel_launch(void* const* d_in, const int* in_sizes, int n_in,
                              void* d_out, int out_size, void* d_ws, size_t ws_size,
                              hipStream_t stream) {
  const float* x      = (const float*)d_in[0];
  const float* ln1_g  = (const float*)d_in[3];
  const float* ln1_b  = (const float*)d_in[4];
  const float* qkv_w  = (const float*)d_in[5];
  const float* qkv_b  = (const float*)d_in[6];
  const float* proj_w = (const float*)d_in[7];
  const float* proj_b = (const float*)d_in[8];
  const float* tau    = (const float*)d_in[9];
  const float* rpb    = (const float*)d_in[10];
  const float* ln2_g  = (const float*)d_in[11];
  const float* ln2_b  = (const float*)d_in[12];
  const float* fc1_w  = (const float*)d_in[13];
  const float* fc1_b  = (const float*)d_in[14];
  const float* fc2_w  = (const float*)d_in[15];
  const float* fc2_b  = (const float*)d_in[16];
  float* out = (float*)d_out;
  char* ws = (char*)d_ws;

  // workspace layout (peak ~244 MiB, buffers reused)
  bf16* wT_qkv  = (bf16*)(ws + 0);            //  884,736 B (1152x384)
  bf16* wT_proj = (bf16*)(ws + 884736);       //  294,912 B (384x384)
  bf16* wT_fc1  = (bf16*)(ws + 1179648);      // 1,179,648 B (1536x384)
  bf16* wT_fc2  = (bf16*)(ws + 2359296);      // 1,179,648 B (384x1536)
  bf16* winb    = (bf16*)(ws + 4194304);      // 50,331,648 B (65536x384)
  bf16* qkvb    = (bf16*)(ws + 54525952);     // 150,994,944 B (65536x1152)
  bf16* attnb   = (bf16*)(ws + 205520896);    // 50,331,648 B (65536x384)
  bf16* xn2b    = winb;                        // reuse (win dead after qkv GEMM)
  bf16* hb      = qkvb;                        // reuse (qkv+attn dead) 201,326,592 B

  // K0: weight conversion+transpose
  wconv_kernel<<<(384 * 1152 + 255) / 256, 256, 0, stream>>>(qkv_w, wT_qkv, 384, 1152);
  wconv_kernel<<<(384 * 384 + 255) / 256, 256, 0, stream>>>(proj_w, wT_proj, 384, 384);
  wconv_kernel<<<(384 * 1536 + 255) / 256, 256, 0, stream>>>(fc1_w, wT_fc1, 384, 1536);
  wconv_kernel<<<(1536 * 384 + 255) / 256, 256, 0, stream>>>(fc2_w, wT_fc2, 1536, 384);

  // K1: LN1 + roll + window partition
  ln_kernel<<<MTOT, 384, 0, stream>>>(x, ln1_g, ln1_b, winb, 1);
  // K2: qkv GEMM (65536 x 1152 x 384), gridN = 9
  gemm_bt<0><<<(MTOT / 128) * (1152 / 128), 256, 0, stream>>>(
      winb, wT_qkv, qkv_b, qkvb, nullptr, nullptr, MTOT, 1152, 384, 1152 / 128);
  // K3: attention
  attn_kernel<<<dim3(NHEADS, 1024), 256, 0, stream>>>(qkvb, tau, rpb, attnb);
  // K4: proj GEMM + window-reverse/roll scatter + residual -> d_out, gridN = 3
  gemm_bt<2><<<(MTOT / 128) * (384 / 128), 256, 0, stream>>>(
      attnb, wT_proj, proj_b, nullptr, out, x, MTOT, 384, 384, 384 / 128);
  // K5: LN2
  ln_kernel<<<MTOT, 384, 0, stream>>>(out, ln2_g, ln2_b, xn2b, 0);
  // K6: fc1 + GELU, gridN = 12
  gemm_bt<1><<<(MTOT / 128) * (HID / 128), 256, 0, stream>>>(
      xn2b, wT_fc1, fc1_b, hb, nullptr, nullptr, MTOT, HID, 384, HID / 128);
  // K7: fc2 += into d_out, gridN = 3
  gemm_bt<3><<<(MTOT / 128) * (384 / 128), 256, 0, stream>>>(
      hb, wT_fc2, fc2_b, nullptr, out, nullptr, MTOT, 384, HID, 384 / 128);
}

// Round 5
// 967.423 us; speedup vs baseline: 1.2748x; 1.0220x over previous
//
#include <hip/hip_runtime.h>
#include <hip/hip_bf16.h>
#include <cstdint>

// ---------------- constants ----------------
#define DIM     384
#define NHEADS  12
#define HD      32
#define HGRID   64          // H = W = 64
#define NTOK    64          // tokens per 8x8 window
#define MTOT    65536       // 16 * 4096 rows
#define HID     1536

typedef __attribute__((ext_vector_type(8))) short bf16x8;
typedef __attribute__((ext_vector_type(4))) float f32x4;
typedef __hip_bfloat16 bf16;

typedef __attribute__((address_space(1))) const void* as1_cvp;
typedef __attribute__((address_space(3))) void*       as3_vp;
#define GLDS16(g, l) __builtin_amdgcn_global_load_lds((as1_cvp)(g), (as3_vp)(l), 16, 0, 0)

// ---------------- K0: weight fp32 (KxN) -> bf16 transposed (NxK) ----------------
__global__ void wconv_kernel(const float* __restrict__ src, bf16* __restrict__ dst,
                             int K, int N) {
  int i = blockIdx.x * 256 + threadIdx.x;
  if (i >= K * N) return;
  int n = i / K, k = i - n * K;
  dst[i] = __float2bfloat16(src[(size_t)k * N + n]);
}

// ---------------- K1/K5: LayerNorm (optionally fused roll+window gather) ----------
// blockIdx.x = OUTPUT row; 384 threads = one per channel.
__global__ __launch_bounds__(384) void ln_kernel(const float* __restrict__ x,
    const float* __restrict__ g, const float* __restrict__ bta,
    bf16* __restrict__ out, int windowed) {
  const int row = blockIdx.x;
  const int c = threadIdx.x;
  size_t src;
  if (windowed) {
    int wg = row >> 6, n = row & 63;
    int b = wg >> 6, wi = wg & 63;
    int hp = ((wi >> 3) << 3) + (n >> 3);
    int wp = ((wi & 7) << 3) + (n & 7);
    int h = (hp + 4) & 63, w = (wp + 4) & 63;   // roll(-4): rolled[i] = x[(i+4)%64]
    src = ((size_t)b * 4096 + h * 64 + w) * DIM;
  } else {
    src = (size_t)row * DIM;
  }
  float v = x[src + c];
  float s = v, ss = v * v;
  #pragma unroll
  for (int off = 32; off; off >>= 1) {
    s  += __shfl_xor(s,  off, 64);
    ss += __shfl_xor(ss, off, 64);
  }
  __shared__ float red[12];
  const int wave = threadIdx.x >> 6, lane = threadIdx.x & 63;
  if (lane == 0) { red[wave] = s; red[6 + wave] = ss; }
  __syncthreads();
  if (threadIdx.x == 0) {
    float ts = 0.f, tss = 0.f;
    #pragma unroll
    for (int i = 0; i < 6; i++) { ts += red[i]; tss += red[6 + i]; }
    red[0] = ts; red[6] = tss;
  }
  __syncthreads();
  const float mean = red[0] * (1.0f / DIM);
  const float var  = red[6] * (1.0f / DIM) - mean * mean;
  const float inv  = rsqrtf(var + 1e-5f);
  out[(size_t)row * DIM + c] = __float2bfloat16((v - mean) * inv * g[c] + bta[c]);
}

// ---------------- GEMM: C = A(MxK) * Bt(NxK)^T, bf16 MFMA 16x16x32 ---------------
// 128x128 tile, BK=64 (A and B both in LDS, 32 KB), 4 waves (each 64x64).
// Halves barrier/vmcnt-drain events vs BK=32 (the measured latency bottleneck:
// R4 counters showed MFMA 17 / VALU 25 / HBM 17 — all idle, drain-bound).
// Row stride 128 B => chunk slot s occupies banks 4s..4s+3 in every row, so
// chunk-XOR swizzle by row: slot = g ^ (R&7) on store, read slot (hh*4+q)^(r&7)
// -> 2-way conflicts = free. Staging: 4 GLDS16 x 8 rows x 128 B per operand.
// XCD-aware 1-D grid remap: all gridN N-blocks of one M-block land consecutive
// on ONE XCD -> A tile fetched once into that XCD's L2 (R4: FETCH 355->157 MB).
// EPI: 0 = +bias -> bf16 out
//      1 = +bias, exact GELU -> bf16 out
//      2 = +bias, window-reverse+roll scatter, + residual x -> f32 out
//      3 = +bias, += into f32 out (row-major)
template <int EPI>
__global__ __launch_bounds__(256) void gemm_bt(
    const bf16* __restrict__ A, const bf16* __restrict__ Bt,
    const float* __restrict__ bias,
    bf16* __restrict__ outb, float* __restrict__ outf,
    const float* __restrict__ resid,
    int M, int N, int K, int gridN)
{
  __shared__ bf16 As[128 * 64];   // 16 KB each, row = 128 B = 8 x 16B chunks
  __shared__ bf16 Bs[128 * 64];
  const int tid = threadIdx.x;
  const int wave = tid >> 6, lane = tid & 63;

  // XCD-aware remap (gridM = M/128 divisible by 8)
  const int bid = blockIdx.x;
  const int xcd = bid & 7, slot = bid >> 3;
  const int n_blk = slot % gridN;
  const int m_blk = (slot / gridN) * 8 + xcd;
  const int m0 = m_blk * 128, n0 = n_blk * 128;

  f32x4 acc[4][4];
  #pragma unroll
  for (int i = 0; i < 4; i++)
    #pragma unroll
    for (int j = 0; j < 4; j++) acc[i][j] = (f32x4){0.f, 0.f, 0.f, 0.f};

  const int q = lane >> 4, r = lane & 15;
  const int mwav = (wave >> 1) * 64, nwav = (wave & 1) * 64;

  // staging: wave covers rows [wave*32, wave*32+32) of A and B, 4 insts each of
  // 8 rows x 128 B. lane l -> dest row +(l>>3), chunk slot l&7.
  // source chunk g = (l&7) ^ (R&7), R&7 = (l>>3)&7 (bases are multiples of 8).
  const int srow = wave * 32 + (lane >> 3);
  const int gchunk = (lane & 7) ^ ((lane >> 3) & 7);
  const char* Ac = (const char*)A + (size_t)(m0 + srow) * K * 2 + gchunk * 16;
  const char* Bc = (const char*)Bt + (size_t)(n0 + srow) * K * 2 + gchunk * 16;
  const size_t rowskip8 = (size_t)8 * K * 2;
  const int ldsbase = wave * 32 * 64;   // element index of this wave's region

  const int rxor = r & 7;

  for (int k0 = 0; k0 < K; k0 += 64) {
    const size_t kb = (size_t)k0 * 2;
    GLDS16(Ac + kb,                &As[ldsbase +  0 * 64]);
    GLDS16(Ac + kb + rowskip8,     &As[ldsbase +  8 * 64]);
    GLDS16(Ac + kb + 2 * rowskip8, &As[ldsbase + 16 * 64]);
    GLDS16(Ac + kb + 3 * rowskip8, &As[ldsbase + 24 * 64]);
    GLDS16(Bc + kb,                &Bs[ldsbase +  0 * 64]);
    GLDS16(Bc + kb + rowskip8,     &Bs[ldsbase +  8 * 64]);
    GLDS16(Bc + kb + 2 * rowskip8, &Bs[ldsbase + 16 * 64]);
    GLDS16(Bc + kb + 3 * rowskip8, &Bs[ldsbase + 24 * 64]);
    __syncthreads();

    #pragma unroll
    for (int hh = 0; hh < 2; hh++) {
      const int s = (hh * 4 + q) ^ rxor;
      bf16x8 af[4], bfr[4];
      #pragma unroll
      for (int mi = 0; mi < 4; mi++)
        af[mi] = *(const bf16x8*)(&As[(mwav + mi * 16 + r) * 64 + s * 8]);
      #pragma unroll
      for (int ni = 0; ni < 4; ni++)
        bfr[ni] = *(const bf16x8*)(&Bs[(nwav + ni * 16 + r) * 64 + s * 8]);
      #pragma unroll
      for (int mi = 0; mi < 4; mi++)
        #pragma unroll
        for (int ni = 0; ni < 4; ni++)
          acc[mi][ni] = __builtin_amdgcn_mfma_f32_16x16x32_bf16(af[mi], bfr[ni], acc[mi][ni], 0, 0, 0);
    }
    __syncthreads();
  }

  // epilogue: D row = (lane>>4)*4 + reg (M), col = lane&15 (N)  [m89-verified]
  #pragma unroll
  for (int mi = 0; mi < 4; mi++) {
    #pragma unroll
    for (int ni = 0; ni < 4; ni++) {
      #pragma unroll
      for (int rr = 0; rr < 4; rr++) {
        const int row = m0 + mwav + mi * 16 + q * 4 + rr;
        const int col = n0 + nwav + ni * 16 + r;
        float val = acc[mi][ni][rr] + bias[col];
        if (EPI == 0) {
          outb[(size_t)row * N + col] = __float2bfloat16(val);
        } else if (EPI == 1) {
          float gl = 0.5f * val * (1.0f + erff(val * 0.70710678118654752f));
          outb[(size_t)row * N + col] = __float2bfloat16(gl);
        } else if (EPI == 2) {
          const int wg = row >> 6, n = row & 63;
          const int b = wg >> 6, wi = wg & 63;
          const int hp = ((wi >> 3) << 3) + (n >> 3);
          const int wp = ((wi & 7) << 3) + (n & 7);
          const int h = (hp + 4) & 63, w = (wp + 4) & 63;  // roll(+4): final[(i+4)%64]=tmp[i]
          const size_t dst = ((size_t)b * 4096 + h * 64 + w) * DIM + col;
          outf[dst] = resid[dst] + val;
        } else {
          outf[(size_t)row * N + col] += val;
        }
      }
    }
  }
}

// ---------------- K3: windowed attention, one block per (window, head) -----------
__device__ __forceinline__ int regid(int v) { return v < 56 ? 0 : (v < 60 ? 1 : 2); }

__global__ __launch_bounds__(256) void attn_kernel(
    const bf16* __restrict__ qkv, const float* __restrict__ tau,
    const float* __restrict__ rpb, bf16* __restrict__ outb)
{
  const int h = blockIdx.x;          // head
  const int w = blockIdx.y;          // global window (b*64 + wy*8 + wx)
  const int t = threadIdx.x;
  const int row = t >> 2, seg = t & 3;

  __shared__ float qs[64][36];
  __shared__ float ks[64][36];
  __shared__ float vs[64][36];
  __shared__ float rpb_s[225];

  // load q/k/v (8 dims per thread), fused l2norm + tau scale
  const size_t base = ((size_t)w * 64 + row) * 1152 + h * 32 + seg * 8;
  float qf[8], kf[8], vf[8];
  {
    uint4 uq = *(const uint4*)(qkv + base);
    uint4 uk = *(const uint4*)(qkv + base + 384);
    uint4 uv = *(const uint4*)(qkv + base + 768);
    const bf16* pq = (const bf16*)&uq;
    const bf16* pk = (const bf16*)&uk;
    const bf16* pv = (const bf16*)&uv;
    #pragma unroll
    for (int i = 0; i < 8; i++) {
      qf[i] = __bfloat162float(pq[i]);
      kf[i] = __bfloat162float(pk[i]);
      vf[i] = __bfloat162float(pv[i]);
    }
  }
  float ssq = 0.f, ssk = 0.f;
  #pragma unroll
  for (int i = 0; i < 8; i++) { ssq += qf[i] * qf[i]; ssk += kf[i] * kf[i]; }
  ssq += __shfl_xor(ssq, 1, 64); ssq += __shfl_xor(ssq, 2, 64);
  ssk += __shfl_xor(ssk, 1, 64); ssk += __shfl_xor(ssk, 2, 64);
  const float qsc = (1.0f / fmaxf(sqrtf(ssq), 1e-12f)) * (1.0f / fmaxf(tau[h], 1e-3f));
  const float ksc = 1.0f / fmaxf(sqrtf(ssk), 1e-12f);
  #pragma unroll
  for (int i = 0; i < 8; i++) {
    qs[row][seg * 8 + i] = qf[i] * qsc;
    ks[row][seg * 8 + i] = kf[i] * ksc;
    vs[row][seg * 8 + i] = vf[i];
  }
  if (t < 225) rpb_s[t] = rpb[t * NHEADS + h];
  __syncthreads();

  float4 qr[8];
  #pragma unroll
  for (int u = 0; u < 8; u++) qr[u] = *(const float4*)&qs[row][u * 4];

  const int wi = w & 63;
  const int wy = wi >> 3, wx = wi & 7;
  const int iy = row >> 3, ix = row & 7;
  const int reg_i = regid(wy * 8 + iy) * 3 + regid(wx * 8 + ix);

  // scores for this row, j = jj*4 + seg (bank-conflict-free interleave)
  float sv[16];
  float mx = -3e38f;
  #pragma unroll
  for (int jj = 0; jj < 16; jj++) {
    const int j = jj * 4 + seg;
    const float4* kr = (const float4*)&ks[j][0];
    float dot = 0.f;
    #pragma unroll
    for (int u = 0; u < 8; u++) {
      float4 kk = kr[u];
      dot += qr[u].x * kk.x; dot += qr[u].y * kk.y;
      dot += qr[u].z * kk.z; dot += qr[u].w * kk.w;
    }
    const int jy = j >> 3, jx = j & 7;
    dot += rpb_s[(iy - jy + 7) * 15 + (ix - jx + 7)];
    const int reg_j = regid(wy * 8 + jy) * 3 + regid(wx * 8 + jx);
    if (reg_j != reg_i) dot -= 1e9f;
    sv[jj] = dot;
    mx = fmaxf(mx, dot);
  }
  mx = fmaxf(mx, __shfl_xor(mx, 1, 64));
  mx = fmaxf(mx, __shfl_xor(mx, 2, 64));
  float sum = 0.f;
  #pragma unroll
  for (int jj = 0; jj < 16; jj++) { sv[jj] = __expf(sv[jj] - mx); sum += sv[jj]; }
  sum += __shfl_xor(sum, 1, 64); sum += __shfl_xor(sum, 2, 64);
  const float rinv = 1.0f / sum;

  float4 po[8];
  #pragma unroll
  for (int u = 0; u < 8; u++) po[u] = make_float4(0.f, 0.f, 0.f, 0.f);
  #pragma unroll
  for (int jj = 0; jj < 16; jj++) {
    const float p = sv[jj] * rinv;
    const float4* vr = (const float4*)&vs[jj * 4 + seg][0];
    #pragma unroll
    for (int u = 0; u < 8; u++) {
      float4 vv = vr[u];
      po[u].x += p * vv.x; po[u].y += p * vv.y;
      po[u].z += p * vv.z; po[u].w += p * vv.w;
    }
  }
  #pragma unroll
  for (int u = 0; u < 8; u++) {
    po[u].x += __shfl_xor(po[u].x, 1, 64); po[u].x += __shfl_xor(po[u].x, 2, 64);
    po[u].y += __shfl_xor(po[u].y, 1, 64); po[u].y += __shfl_xor(po[u].y, 2, 64);
    po[u].z += __shfl_xor(po[u].z, 1, 64); po[u].z += __shfl_xor(po[u].z, 2, 64);
    po[u].w += __shfl_xor(po[u].w, 1, 64); po[u].w += __shfl_xor(po[u].w, 2, 64);
  }
  // each thread writes its 8 dims: float4 indices seg*2, seg*2+1 (static select)
  float4 o0, o1;
  switch (seg) {
    case 0: o0 = po[0]; o1 = po[1]; break;
    case 1: o0 = po[2]; o1 = po[3]; break;
    case 2: o0 = po[4]; o1 = po[5]; break;
    default: o0 = po[6]; o1 = po[7]; break;
  }
  union { uint4 u; bf16 b[8]; } ou;
  ou.b[0] = __float2bfloat16(o0.x); ou.b[1] = __float2bfloat16(o0.y);
  ou.b[2] = __float2bfloat16(o0.z); ou.b[3] = __float2bfloat16(o0.w);
  ou.b[4] = __float2bfloat16(o1.x); ou.b[5] = __float2bfloat16(o1.y);
  ou.b[6] = __float2bfloat16(o1.z); ou.b[7] = __float2bfloat16(o1.w);
  *(uint4*)(outb + ((size_t)w * 64 + row) * DIM + h * 32 + seg * 8) = ou.u;
}

// ---------------- host launch ----------------
extern "C" void kernel_launch(void* const* d_in, const int* in_sizes, int n_in,
                              void* d_out, int out_size, void* d_ws, size_t ws_size,
                              hipStream_t stream) {
  const float* x      = (const float*)d_in[0];
  const float* ln1_g  = (const float*)d_in[3];
  const float* ln1_b  = (const float*)d_in[4];
  const float* qkv_w  = (const float*)d_in[5];
  const float* qkv_b  = (const float*)d_in[6];
  const float* proj_w = (const float*)d_in[7];
  const float* proj_b = (const float*)d_in[8];
  const float* tau    = (const float*)d_in[9];
  const float* rpb    = (const float*)d_in[10];
  const float* ln2_g  = (const float*)d_in[11];
  const float* ln2_b  = (const float*)d_in[12];
  const float* fc1_w  = (const float*)d_in[13];
  const float* fc1_b  = (const float*)d_in[14];
  const float* fc2_w  = (const float*)d_in[15];
  const float* fc2_b  = (const float*)d_in[16];
  float* out = (float*)d_out;
  char* ws = (char*)d_ws;

  // workspace layout (peak ~244 MiB, buffers reused)
  bf16* wT_qkv  = (bf16*)(ws + 0);            //  884,736 B (1152x384)
  bf16* wT_proj = (bf16*)(ws + 884736);       //  294,912 B (384x384)
  bf16* wT_fc1  = (bf16*)(ws + 1179648);      // 1,179,648 B (1536x384)
  bf16* wT_fc2  = (bf16*)(ws + 2359296);      // 1,179,648 B (384x1536)
  bf16* winb    = (bf16*)(ws + 4194304);      // 50,331,648 B (65536x384)
  bf16* qkvb    = (bf16*)(ws + 54525952);     // 150,994,944 B (65536x1152)
  bf16* attnb   = (bf16*)(ws + 205520896);    // 50,331,648 B (65536x384)
  bf16* xn2b    = winb;                        // reuse (win dead after qkv GEMM)
  bf16* hb      = qkvb;                        // reuse (qkv+attn dead) 201,326,592 B

  // K0: weight conversion+transpose
  wconv_kernel<<<(384 * 1152 + 255) / 256, 256, 0, stream>>>(qkv_w, wT_qkv, 384, 1152);
  wconv_kernel<<<(384 * 384 + 255) / 256, 256, 0, stream>>>(proj_w, wT_proj, 384, 384);
  wconv_kernel<<<(384 * 1536 + 255) / 256, 256, 0, stream>>>(fc1_w, wT_fc1, 384, 1536);
  wconv_kernel<<<(1536 * 384 + 255) / 256, 256, 0, stream>>>(fc2_w, wT_fc2, 1536, 384);

  // K1: LN1 + roll + window partition
  ln_kernel<<<MTOT, 384, 0, stream>>>(x, ln1_g, ln1_b, winb, 1);
  // K2: qkv GEMM (65536 x 1152 x 384), gridN = 9
  gemm_bt<0><<<(MTOT / 128) * (1152 / 128), 256, 0, stream>>>(
      winb, wT_qkv, qkv_b, qkvb, nullptr, nullptr, MTOT, 1152, 384, 1152 / 128);
  // K3: attention
  attn_kernel<<<dim3(NHEADS, 1024), 256, 0, stream>>>(qkvb, tau, rpb, attnb);
  // K4: proj GEMM + window-reverse/roll scatter + residual -> d_out, gridN = 3
  gemm_bt<2><<<(MTOT / 128) * (384 / 128), 256, 0, stream>>>(
      attnb, wT_proj, proj_b, nullptr, out, x, MTOT, 384, 384, 384 / 128);
  // K5: LN2
  ln_kernel<<<MTOT, 384, 0, stream>>>(out, ln2_g, ln2_b, xn2b, 0);
  // K6: fc1 + GELU, gridN = 12
  gemm_bt<1><<<(MTOT / 128) * (HID / 128), 256, 0, stream>>>(
      xn2b, wT_fc1, fc1_b, hb, nullptr, nullptr, MTOT, HID, 384, HID / 128);
  // K7: fc2 += into d_out, gridN = 3
  gemm_bt<3><<<(MTOT / 128) * (384 / 128), 256, 0, stream>>>(
      hb, wT_fc2, fc2_b, nullptr, out, nullptr, MTOT, 384, HID, 384 / 128);
}